// Round 1
// 180.873 us; speedup vs baseline: 1.0178x; 1.0178x over previous
//
#include <hip/hip_runtime.h>
#include <hip/hip_bf16.h>
#include <stdint.h>

#define IN_F 128
#define OUT_F 16
#define NEG_SLOPE 0.2f
#define LB_BITS 7               // bucket = 128 nodes (agg-tile granular scatter)
#define LB_NODES 128
#define NB 782                  // ceil(100000/128)
#define CAP 4608                // per-bucket capacity (mean 4096, +8 sigma)
#define SC_E 8192               // edges per scatter block

// scatter LDS: hist/pref/gbase/rank (4*782*4=12512) + tsum (1024) + sortedP 32K
#define SMEM_BYTES (12512 + 1024 + SC_E * 4)

__device__ __forceinline__ float u2f(uint32_t u) {
  union { uint32_t i; float f; } c;
  c.i = u;
  return c.f;
}

// ---------------------------------------------------------------------------
// Fused proj + scatter. Projection: one thread per node (streams its 512 B
// h-row once, acc[16] in registers, W broadcast from LDS). Scatter: bins
// edges at 128-node granularity (782 buckets) so the agg kernel's payload
// region is exactly its tile -> no quad filtering in agg.
// ---------------------------------------------------------------------------
__global__ __launch_bounds__(256) void proj_scatter_kernel(
    const float* __restrict__ h, const float* __restrict__ W,
    const float* __restrict__ a_l, const float* __restrict__ a_r,
    const int* __restrict__ src, const int* __restrict__ dst,
    __hip_bfloat16* __restrict__ hWbf, float* __restrict__ el,
    float* __restrict__ er, int* __restrict__ cursor,
    uint32_t* __restrict__ payload, int N, int E, int scatBlocks) {
  __shared__ __align__(16) uint8_t smem[SMEM_BYTES];
  int t = threadIdx.x;

  if ((int)blockIdx.x < scatBlocks) {
    // ---------------- scatter branch: 782-bucket bin ----------------
    int* hist = (int*)smem;          // NB
    int* pref = hist + NB;
    int* gbase = pref + NB;
    int* rank = gbase + NB;
    int* tsum = rank + NB;           // 256
    uint32_t* sortedP = (uint32_t*)(tsum + 256);  // SC_E

    int start = blockIdx.x * SC_E;
    int end = min(E, start + SC_E);
    int cnt = end - start;

    for (int i = t; i < NB; i += 256) { hist[i] = 0; rank[i] = 0; }
    __syncthreads();

    const int4* d4 = (const int4*)(dst + start);
    int n4 = cnt >> 2;
    for (int i = t; i < n4; i += 256) {
      int4 d = d4[i];
      atomicAdd(&hist[d.x >> LB_BITS], 1);
      atomicAdd(&hist[d.y >> LB_BITS], 1);
      atomicAdd(&hist[d.z >> LB_BITS], 1);
      atomicAdd(&hist[d.w >> LB_BITS], 1);
    }
    for (int i = start + (n4 << 2) + t; i < end; i += 256)
      atomicAdd(&hist[dst[i] >> LB_BITS], 1);
    __syncthreads();

    // two-level exclusive prefix over 782 buckets + global range reservation
    {
      int b0 = t * 4;
      int s_loc = 0;
      if (b0 < NB) {
        int lim = min(b0 + 4, NB);
        for (int j = b0; j < lim; ++j) s_loc += hist[j];
      }
      tsum[t] = s_loc;
    }
    __syncthreads();
    {
      int pre = 0;
      for (int j = 0; j < t; ++j) pre += tsum[j];  // independent loads, pipelined
      int b0 = t * 4;
      if (b0 < NB) {
        int lim = min(b0 + 4, NB);
        int run = pre;
        for (int j = b0; j < lim; ++j) {
          pref[j] = run;
          int c = hist[j];
          run += c;
          gbase[j] = c ? atomicAdd(&cursor[j * 16], c) : 0;  // cursor pre-zeroed
        }
      }
    }
    __syncthreads();

    const int4* s4 = (const int4*)(src + start);
    for (int i = t; i < n4; i += 256) {
      int4 d = d4[i];
      int4 s = s4[i];
#pragma unroll
      for (int j = 0; j < 4; ++j) {
        int dd = j == 0 ? d.x : j == 1 ? d.y : j == 2 ? d.z : d.w;
        int ss = j == 0 ? s.x : j == 1 ? s.y : j == 2 ? s.z : s.w;
        int b = dd >> LB_BITS;
        int r = atomicAdd(&rank[b], 1);
        sortedP[pref[b] + r] =
            ((uint32_t)ss << LB_BITS) | (uint32_t)(dd & (LB_NODES - 1));
      }
    }
    for (int i = start + (n4 << 2) + t; i < end; i += 256) {
      int dd = dst[i];
      int b = dd >> LB_BITS;
      int r = atomicAdd(&rank[b], 1);
      sortedP[pref[b] + r] =
          ((uint32_t)src[i] << LB_BITS) | (uint32_t)(dd & (LB_NODES - 1));
    }
    __syncthreads();

    // write-out: 16-lane group per bucket run (runs avg ~10 entries)
    int g16 = t >> 4, l16 = t & 15;
    for (int b = g16; b < NB; b += 16) {
      int c = hist[b];
      if (c == 0) continue;
      int p0 = pref[b];
      int gb = gbase[b];
      size_t g0 = (size_t)b * CAP + (size_t)gb;
      for (int j = l16; j < c; j += 16)
        if (gb + j < CAP) payload[g0 + j] = sortedP[p0 + j];
    }
  } else {
    // ---------------- projection branch: one thread per node ----------------
    float* Ws = (float*)smem;  // 16*128 floats = 8 KB (wave-uniform broadcast)
    for (int i = t; i < OUT_F * IN_F; i += 256) Ws[i] = W[i];
    __syncthreads();

    int node = ((int)blockIdx.x - scatBlocks) * 256 + t;
    if (node >= N) return;

    const float4* hrow = (const float4*)(h + (size_t)node * IN_F);
    float acc[OUT_F];
#pragma unroll
    for (int f = 0; f < OUT_F; ++f) acc[f] = 0.f;

#pragma unroll 4
    for (int k = 0; k < IN_F / 4; ++k) {
      float4 hv = hrow[k];
#pragma unroll
      for (int f = 0; f < OUT_F; ++f) {
        float4 wv = ((const float4*)(Ws + f * IN_F))[k];  // uniform -> bcast
        acc[f] += hv.x * wv.x + hv.y * wv.y + hv.z * wv.z + hv.w * wv.w;
      }
    }

    union {
      unsigned short us[OUT_F];
      uint4 q[2];
    } pk;
#pragma unroll
    for (int f = 0; f < OUT_F; ++f) {
      __hip_bfloat16 b = __float2bfloat16(acc[f]);
      pk.us[f] = *reinterpret_cast<unsigned short*>(&b);
    }
    uint4* dstq = (uint4*)(hWbf + (size_t)node * OUT_F);
    dstq[0] = pk.q[0];
    dstq[1] = pk.q[1];

    float vl = 0.f, vr = 0.f;
#pragma unroll
    for (int f = 0; f < OUT_F; ++f) {
      vl += acc[f] * a_l[f];
      vr += acc[f] * a_r[f];
    }
    el[node] = vl;
    er[node] = vr;
  }
}

// ---------------------------------------------------------------------------
// Aggregation: one block per 128-node bucket. Payload region IS the tile ->
// pass 1 is a straight coalesced copy fused with the histogram (no ballot
// compaction, 1x read instead of 4x). Pass 6: 4 lanes per node, uint2
// (4 x bf16) gathers from L2-resident hWbf.
// ---------------------------------------------------------------------------
__global__ __launch_bounds__(512) void agg_kernel(
    const uint32_t* __restrict__ payload, const int* __restrict__ cursor,
    const __hip_bfloat16* __restrict__ hWbf, const float* __restrict__ el,
    const float* __restrict__ er, float* __restrict__ out, int N) {
  __shared__ __align__(16) uint32_t sorted[CAP];  // 18 KB
  __shared__ __align__(16) float exS[CAP];        // 18 KB (aliased as kept[])
  __shared__ int hist[LB_NODES];
  __shared__ int pref[LB_NODES];
  __shared__ int rank[LB_NODES];
  uint32_t* kept = (uint32_t*)exS;

  int t = threadIdx.x;
  int b = blockIdx.x;
  size_t base = (size_t)b * CAP;
  int cnt = min(cursor[b * 16], CAP);
  int node0 = b << LB_BITS;

  if (t < LB_NODES) { hist[t] = 0; rank[t] = 0; }
  __syncthreads();

  // pass 1: straight copy + fused histogram
  const uint4* pay4 = (const uint4*)(payload + base);  // CAP%4==0
  uint4* kept4 = (uint4*)kept;
  int n4 = (cnt + 3) >> 2;
  for (int i = t; i < n4; i += 512) {
    uint4 v = pay4[i];
    kept4[i] = v;
    int i0 = i << 2;
    if (i0 + 0 < cnt) atomicAdd(&hist[v.x & (LB_NODES - 1)], 1);
    if (i0 + 1 < cnt) atomicAdd(&hist[v.y & (LB_NODES - 1)], 1);
    if (i0 + 2 < cnt) atomicAdd(&hist[v.z & (LB_NODES - 1)], 1);
    if (i0 + 3 < cnt) atomicAdd(&hist[v.w & (LB_NODES - 1)], 1);
  }
  __syncthreads();

  // pass 2: prefix over 128
  if (t < LB_NODES) {
    int s = 0;
    for (int j = 0; j < t; ++j) s += hist[j];
    pref[t] = s;
  }
  __syncthreads();

  // pass 3: place kept -> sorted
  for (int i = t; i < cnt; i += 512) {
    uint32_t p = kept[i];
    int dl = (int)(p & (LB_NODES - 1));
    int r = atomicAdd(&rank[dl], 1);
    sorted[pref[dl] + r] = p;
  }
  __syncthreads();

  // pass 4: exp once per edge (overwrites kept — dead after pass 3)
  for (int i = t; i < cnt; i += 512) {
    uint32_t p = sorted[i];
    float x = el[p >> LB_BITS] + er[node0 + (int)(p & (LB_NODES - 1))];
    x = x > 0.f ? x : NEG_SLOPE * x;
    exS[i] = __expf(x);
  }
  __syncthreads();

  // pass 5: 4 lanes per node, uint2 (4 bf16) gather, register CSR
  int g = t >> 2, f4 = t & 3;
  int node = node0 + g;
  if (node < N) {
    int k = pref[g];
    int kend = k + hist[g];
    float a0 = 0.f, a1 = 0.f, a2 = 0.f, a3 = 0.f, es = 0.f;
    const uint2* hw2 = (const uint2*)hWbf;
#pragma unroll 4
    for (; k < kend; ++k) {
      uint32_t p = sorted[k];
      float ex = exS[k];
      uint2 w = hw2[(size_t)(p >> LB_BITS) * 4 + f4];
      a0 += ex * u2f(w.x << 16);
      a1 += ex * u2f(w.x & 0xffff0000u);
      a2 += ex * u2f(w.y << 16);
      a3 += ex * u2f(w.y & 0xffff0000u);
      es += ex;
    }
    float inv = 1.0f / fmaxf(es, 1e-16f);
    float4 o = make_float4(a0 * inv, a1 * inv, a2 * inv, a3 * inv);
    ((float4*)(out + (size_t)node * OUT_F))[f4] = o;
  }
}

extern "C" void kernel_launch(void* const* d_in, const int* in_sizes, int n_in,
                              void* d_out, int out_size, void* d_ws, size_t ws_size,
                              hipStream_t stream) {
  const float* h   = (const float*)d_in[0];
  const int*   src = (const int*)d_in[1];
  const int*   dst = (const int*)d_in[2];
  const float* W   = (const float*)d_in[3];
  const float* a_l = (const float*)d_in[4];
  const float* a_r = (const float*)d_in[5];
  float* out = (float*)d_out;

  const int N = in_sizes[0] / IN_F;
  const int E = in_sizes[1];
  const int scatBlocks = (E + SC_E - 1) / SC_E;      // 391
  const int projBlocks = (N + 255) / 256;            // 391 (1 thread/node)

  // ws: hWbf (bf16) | el | er | cursor | payload
  __hip_bfloat16* hWbf = (__hip_bfloat16*)d_ws;        // N*16 bf16 = 3.2 MB
  float* el = (float*)(hWbf + (size_t)N * OUT_F);      // N
  float* er = el + N;                                  // N
  int* cursor = (int*)(er + N);                        // NB*16 (line-strided)
  uint32_t* payload = (uint32_t*)(cursor + (size_t)NB * 16);  // NB*CAP = 14.4 MB

  hipMemsetAsync(cursor, 0, (size_t)NB * 16 * sizeof(int), stream);

  proj_scatter_kernel<<<scatBlocks + projBlocks, 256, 0, stream>>>(
      h, W, a_l, a_r, src, dst, hWbf, el, er, cursor, payload, N, E, scatBlocks);

  agg_kernel<<<NB, 512, 0, stream>>>(payload, cursor, hWbf, el, er, out, N);
}